// Round 7
// baseline (265.140 us; speedup 1.0000x reference)
//
#include <hip/hip_runtime.h>

#define D 128
#define NH 8

typedef __bf16 bf16x8 __attribute__((ext_vector_type(8)));
typedef unsigned short ushortx8 __attribute__((ext_vector_type(8)));
typedef float floatx4 __attribute__((ext_vector_type(4)));

__device__ __forceinline__ float bf2f(unsigned short u) {
  union { unsigned int i; float f; } x; x.i = ((unsigned int)u) << 16; return x.f;
}
__device__ __forceinline__ unsigned short f2bf(float f) {
  union { float f; unsigned int i; } x; x.f = f;
  unsigned int i = x.i;
  return (unsigned short)((i + 0x7FFFu + ((i >> 16) & 1u)) >> 16);
}
// accumulate both bf16 halves of packed uints into s
__device__ __forceinline__ void acc2(unsigned int ku, unsigned int qu, float& s) {
  union { unsigned int i; float f; } a, b;
  a.i = ku << 16;          b.i = qu << 16;          s += a.f * b.f;
  a.i = ku & 0xffff0000u;  b.i = qu & 0xffff0000u;  s += a.f * b.f;
}

// ---------------------------------------------------------------- transform + hist
// blocks [0,384): weight fold; blocks [384,...): dst histogram (counts pre-zeroed)
__global__ __launch_bounds__(256) void k_misc(
    const float* __restrict__ Wk, const float* __restrict__ bk,
    const float* __restrict__ Wq, const float* __restrict__ bq,
    const float* __restrict__ Wv, const float* __restrict__ bv,
    const float* __restrict__ rel_att, const float* __restrict__ rel_msg,
    const float* __restrict__ rel_pri,
    const float* __restrict__ wm0, const float* __restrict__ wm1,
    const float* __restrict__ wm2,
    unsigned short* __restrict__ Wt_all, float* __restrict__ bias_all,
    const int* __restrict__ dst, int* __restrict__ counts, int E)
{
  int b = blockIdx.x;
  if (b >= 384) {
    int e = (b - 384) * 256 + threadIdx.x;
    if (e < E) atomicAdd(&counts[dst[e]], 1);
    return;
  }
  int gid = b * 256 + threadIdx.x;
  if (gid >= 6 * 128 * 128) return;
  int p = gid >> 14;
  int idx = gid & 16383;
  int c = idx >> 7, k = idx & 127;
  int h = c >> 4, r = c & 15;
  float wsum = 0.f, bsum = 0.f;
  if (p == 0) {
    wsum = Wk[k * 128 + c];
    bsum = bk[c];
  } else if (p <= 4) {
    const float* M = (p == 1) ? rel_att : ((p == 2) ? wm0 : ((p == 3) ? wm1 : wm2));
#pragma unroll
    for (int f = 0; f < 16; f++) {
      float mv = M[h * 256 + r * 16 + f];
      wsum += Wq[k * 128 + h * 16 + f] * mv;
      bsum += bq[h * 16 + f] * mv;
    }
    if (p == 1) { float sc = rel_pri[h] * 2.5f; wsum *= sc; bsum *= sc; }
  } else {
#pragma unroll
    for (int d = 0; d < 16; d++) {
      float mv = rel_msg[h * 256 + d * 16 + r];
      wsum += Wv[k * 128 + h * 16 + d] * mv;
      bsum += bv[h * 16 + d] * mv;
    }
  }
  Wt_all[(size_t)p * 16384 + c * 128 + k] = f2bf(wsum);
  if (k == 0) bias_all[p * 128 + c] = bsum;
}

// ---------------------------------------------------------------- projections + assign
// grid (157, 4), 512 threads. y<3: 128-row GEMM tiles for modality y across the
// 4 weight planes. y==3,x==0: unordered CSR segment assignment via wave-scan +
// one atomicAdd per wave on a global allocator (no ordered scan needed).
__global__ __launch_bounds__(512) void k_proj(
    const float* __restrict__ x0, const float* __restrict__ x1,
    const float* __restrict__ x2,
    const unsigned short* __restrict__ Wt_all, const float* __restrict__ bias_all,
    unsigned short* __restrict__ P,
    const int* __restrict__ counts, int* __restrict__ row_start,
    int* __restrict__ alloc, int N)
{
  if (blockIdx.y == 3) {
    if (blockIdx.x != 0) return;
    int tid = threadIdx.x, lane = tid & 63;
    for (int base = 0; base < N; base += 512) {
      int n = base + tid;
      int cnt = (n < N) ? counts[n] : 0;
      int x = cnt;
#pragma unroll
      for (int off = 1; off < 64; off <<= 1) {
        int y = __shfl_up(x, off, 64);
        if (lane >= off) x += y;
      }
      int wtot = __shfl(x, 63, 64);
      int wbase = 0;
      if (lane == 63) wbase = atomicAdd(alloc, wtot);
      wbase = __shfl(wbase, 63, 64);
      if (n < N) row_start[n] = wbase + x - cnt;
    }
    return;
  }
  __shared__ __attribute__((aligned(16))) unsigned short Wt[128 * 136];
  int m = blockIdx.y;
  const float* X = (m == 0) ? x0 : ((m == 1) ? x1 : x2);
  int tid = threadIdx.x;
  int wave = tid >> 6, lane = tid & 63;
  int quad = lane >> 4, l16 = lane & 15;
  int row0 = blockIdx.x * 128 + wave * 16;
  int arow = row0 + l16; if (arow >= N) arow = N - 1;
  const float* ap = X + (size_t)arow * D;
  bf16x8 afr[4];
#pragma unroll
  for (int kk4 = 0; kk4 < 4; kk4++) {
    float4 f0 = *(const float4*)(ap + kk4 * 32 + quad * 8);
    float4 f1 = *(const float4*)(ap + kk4 * 32 + quad * 8 + 4);
    ushortx8 uu;
    uu[0]=f2bf(f0.x); uu[1]=f2bf(f0.y); uu[2]=f2bf(f0.z); uu[3]=f2bf(f0.w);
    uu[4]=f2bf(f1.x); uu[5]=f2bf(f1.y); uu[6]=f2bf(f1.z); uu[7]=f2bf(f1.w);
    afr[kk4] = __builtin_bit_cast(bf16x8, uu);
  }
  for (int pt = 0; pt < 4; pt++) {
    int wp = (pt == 0) ? 0 : ((pt == 1) ? 1 : ((pt == 2) ? (2 + m) : 5));
    const unsigned short* Wsrc = Wt_all + (size_t)wp * 16384;
    const float* B = bias_all + wp * 128;
    __syncthreads();
#pragma unroll
    for (int it = 0; it < 4; it++) {              // 2048 uint4 = 32 KB
      int idx = it * 512 + tid;
      int c = idx >> 4, kc = (idx & 15) << 3;
      *(uint4*)(&Wt[c * 136 + kc]) = *(const uint4*)(&Wsrc[c * 128 + kc]);
    }
    __syncthreads();
    floatx4 acc[8];
#pragma unroll
    for (int ct = 0; ct < 8; ct++) acc[ct] = (floatx4)0.f;
#pragma unroll
    for (int kk4 = 0; kk4 < 4; kk4++) {
#pragma unroll
      for (int ct = 0; ct < 8; ct++) {
        uint4 bu = *(const uint4*)(&Wt[(ct * 16 + l16) * 136 + kk4 * 32 + quad * 8]);
        bf16x8 bf = __builtin_bit_cast(bf16x8, bu);
        acc[ct] = __builtin_amdgcn_mfma_f32_16x16x32_bf16(afr[kk4], bf, acc[ct], 0, 0, 0);
      }
    }
    unsigned short* Pout = P + (size_t)(pt * 3 + m) * N * D;
#pragma unroll
    for (int ct = 0; ct < 8; ct++) {
      int col = ct * 16 + l16;
      float bias = B[col];
#pragma unroll
      for (int i = 0; i < 4; i++) {
        int r = row0 + quad * 4 + i;
        if (r < N) Pout[(size_t)r * D + col] = f2bf(acc[ct][i] + bias);
      }
    }
  }
}

// ---------------------------------------------------------------- scatter src -> CSR
__global__ void k_scatter(const int* __restrict__ dst, const int* __restrict__ src,
                          const int* __restrict__ row_start,
                          int* __restrict__ cursor, int* __restrict__ src_sorted, int E) {
  int e = blockIdx.x * 256 + threadIdx.x;
  if (e < E) {
    int d = dst[e];
    int pos = atomicAdd(&cursor[d], 1);
    src_sorted[row_start[d] + pos] = src[e];
  }
}

// ---------------------------------------------------------------- fused node kernel
// q-slices live in LDS (per-wave 6x256B, broadcast reads) to cut VGPR.
__device__ __forceinline__ void edge_vals_lds(
    const unsigned short* __restrict__ P, size_t Nsz, int s, int h,
    const uint4* __restrict__ q,
    float (&av)[3], float (&lv)[3])
{
#pragma unroll
  for (int m = 0; m < 3; m++) {
    const unsigned short* kp = P + ((size_t)m * Nsz + s) * 128 + h * 16;
    uint4 k0 = *(const uint4*)kp, k1 = *(const uint4*)(kp + 8);
    uint4 a0 = q[m * 16 + h * 2], a1 = q[m * 16 + h * 2 + 1];
    uint4 w0 = q[(3 + m) * 16 + h * 2], w1 = q[(3 + m) * 16 + h * 2 + 1];
    const unsigned int* ka = (const unsigned int*)&k0;
    const unsigned int* kb = (const unsigned int*)&k1;
    const unsigned int* pa0 = (const unsigned int*)&a0;
    const unsigned int* pa1 = (const unsigned int*)&a1;
    const unsigned int* pw0 = (const unsigned int*)&w0;
    const unsigned int* pw1 = (const unsigned int*)&w1;
    float da = 0.f, dw = 0.f;
#pragma unroll
    for (int j = 0; j < 4; j++) {
      acc2(ka[j], pa0[j], da); acc2(kb[j], pa1[j], da);
      acc2(ka[j], pw0[j], dw); acc2(kb[j], pw1[j], dw);
    }
    av[m] = da;          // rel_pri*2.5 folded into QA plane
    lv[m] = dw;
  }
  float mx = fmaxf(lv[0], fmaxf(lv[1], lv[2]));
  float e0 = __expf(lv[0] - mx), e1 = __expf(lv[1] - mx), e2 = __expf(lv[2] - mx);
  float inv = 1.f / (e0 + e1 + e2);
  lv[0] = e0 * inv; lv[1] = e1 * inv; lv[2] = e2 * inv;
}

// one wave per dst node; 2-chunk register cache (deg<=16 fast path, P(>16)~0.4%).
__global__ __launch_bounds__(256, 5) void k_node(
    const unsigned short* __restrict__ P,
    const int* __restrict__ row_start, const int* __restrict__ counts,
    const int* __restrict__ srcs,
    unsigned short* __restrict__ hagg, int N, int E)
{
  __shared__ __attribute__((aligned(16))) uint4 qsh[4 * 96];
  int tid = threadIdx.x;
  int wave = tid >> 6, lane = tid & 63;
  int n = blockIdx.x * 4 + wave;
  if (n >= N) return;
  int ro = row_start[n];
  int deg = counts[n];
  float acc00 = 0, acc01 = 0, acc10 = 0, acc11 = 0, acc20 = 0, acc21 = 0;
  if (deg > 0) {
    int h = lane & 7, slot = lane >> 3;
    size_t Nsz = (size_t)N;
    uint4* q = &qsh[wave * 96];
    // stage qa (planes 3..5) and qw (planes 6..8) rows for node n: 6 x 256 B
    for (int idx = lane; idx < 96; idx += 64) {
      int row = idx >> 4, col = idx & 15;
      q[idx] = *(const uint4*)(P + ((size_t)(3 + row) * Nsz + n) * 128 + col * 8);
    }
    // wave-private LDS region: in-wave ds ordering suffices, no barrier
    int nch = (deg + 7) >> 3;
    float cX0[2] = {}, cX1[2] = {}, cX2[2] = {}, cEa[2] = {}, cT[2] = {};
    int cS[2] = {};
    // ---- phase 1: sumA_m, sumAl
    float sA0 = 0, sA1 = 0, sA2 = 0, sAl = 0;
#pragma unroll
    for (int c = 0; c < 2; c++) {
      int idx = c * 8 + slot;
      if (c < nch && idx < deg) {
        int s = srcs[ro + idx]; cS[c] = s;
        float av[3], lv[3];
        edge_vals_lds(P, Nsz, s, h, q, av, lv);
        float e0 = __expf(av[0]), e1 = __expf(av[1]), e2 = __expf(av[2]);
        float align = -(fabsf(av[0]-av[1]) + fabsf(av[0]-av[2]) + fabsf(av[1]-av[2])) * (1.f/3.f);
        float ea = __expf(align);
        cX0[c] = lv[0] * e0; cX1[c] = lv[1] * e1; cX2[c] = lv[2] * e2; cEa[c] = ea;
        sA0 += e0; sA1 += e1; sA2 += e2; sAl += ea;
      }
    }
    for (int c = 2; c < nch; c++) {          // rare deg>16 fallback
      int idx = c * 8 + slot;
      if (idx < deg) {
        int s = srcs[ro + idx];
        float av[3], lv[3];
        edge_vals_lds(P, Nsz, s, h, q, av, lv);
        float align = -(fabsf(av[0]-av[1]) + fabsf(av[0]-av[2]) + fabsf(av[1]-av[2])) * (1.f/3.f);
        sA0 += __expf(av[0]); sA1 += __expf(av[1]); sA2 += __expf(av[2]);
        sAl += __expf(align);
      }
    }
#pragma unroll
    for (int off = 8; off < 64; off <<= 1) {
      sA0 += __shfl_xor(sA0, off, 64);
      sA1 += __shfl_xor(sA1, off, 64);
      sA2 += __shfl_xor(sA2, off, 64);
      sAl += __shfl_xor(sAl, off, 64);
    }
    float rA0 = 1.f / fmaxf(sA0, 1e-30f), rA1 = 1.f / fmaxf(sA1, 1e-30f);
    float rA2 = 1.f / fmaxf(sA2, 1e-30f), rAl = 1.f / fmaxf(sAl, 1e-30f);
    // ---- phase 2: sumT
    float sT = 0;
#pragma unroll
    for (int c = 0; c < 2; c++) {
      int idx = c * 8 + slot;
      if (c < nch && idx < deg) {
        float t = (cX0[c] * rA0 + cX1[c] * rA1 + cX2[c] * rA2) * (cEa[c] * rAl);
        cT[c] = t;
        sT += __expf(t);
      }
    }
    for (int c = 2; c < nch; c++) {
      int idx = c * 8 + slot;
      if (idx < deg) {
        int s = srcs[ro + idx];
        float av[3], lv[3];
        edge_vals_lds(P, Nsz, s, h, q, av, lv);
        float align = -(fabsf(av[0]-av[1]) + fabsf(av[0]-av[2]) + fabsf(av[1]-av[2])) * (1.f/3.f);
        float t = (lv[0]*__expf(av[0])*rA0 + lv[1]*__expf(av[1])*rA1 + lv[2]*__expf(av[2])*rA2)
                  * (__expf(align) * rAl);
        sT += __expf(t);
      }
    }
#pragma unroll
    for (int off = 8; off < 64; off <<= 1) sT += __shfl_xor(sT, off, 64);
    float rT = 1.f / fmaxf(sT, 1e-30f);
    // ---- phase 3: beta + aggregation, fully unrolled + predicated
    const unsigned int* Pu = (const unsigned int*)P;
    int hl = lane >> 3;
#pragma unroll
    for (int c = 0; c < 2; c++) {
      if (c < nch) {
        int idx = c * 8 + slot;
        float beta = (idx < deg) ? __expf(cT[c]) * rT : 0.f;
        int sv = cS[c];          // 0 for invalid slots (cached node-0 row, b=0)
        float bj[8]; int sj[8];
#pragma unroll
        for (int jj = 0; jj < 8; jj++) {
          bj[jj] = __shfl(beta, jj * 8 + hl, 64);
          sj[jj] = __shfl(sv, jj * 8, 64);
        }
#pragma unroll
        for (int jj = 0; jj < 8; jj++) {
          size_t base9 = ((size_t)9 * Nsz + sj[jj]) * 64 + lane;
          unsigned int u0 = Pu[base9];
          unsigned int u1 = Pu[base9 + Nsz * 64];
          unsigned int u2 = Pu[base9 + 2 * Nsz * 64];
          float b = bj[jj];
          acc00 += b * bf2f((unsigned short)u0); acc01 += b * bf2f((unsigned short)(u0 >> 16));
          acc10 += b * bf2f((unsigned short)u1); acc11 += b * bf2f((unsigned short)(u1 >> 16));
          acc20 += b * bf2f((unsigned short)u2); acc21 += b * bf2f((unsigned short)(u2 >> 16));
        }
      }
    }
    for (int c = 2; c < nch; c++) {          // rare deg>16 fallback
      int idx = c * 8 + slot;
      float beta = 0.f; int sv = 0;
      if (idx < deg) {
        sv = srcs[ro + idx];
        float av[3], lv[3];
        edge_vals_lds(P, Nsz, sv, h, q, av, lv);
        float align = -(fabsf(av[0]-av[1]) + fabsf(av[0]-av[2]) + fabsf(av[1]-av[2])) * (1.f/3.f);
        float t = (lv[0]*__expf(av[0])*rA0 + lv[1]*__expf(av[1])*rA1 + lv[2]*__expf(av[2])*rA2)
                  * (__expf(align) * rAl);
        beta = __expf(t) * rT;
      }
      int jmax = min(8, deg - c * 8);
      for (int jj = 0; jj < jmax; jj++) {
        float b = __shfl(beta, jj * 8 + hl, 64);
        int s = __shfl(sv, jj * 8, 64);
        size_t base9 = ((size_t)9 * Nsz + s) * 64 + lane;
        unsigned int u0 = Pu[base9];
        unsigned int u1 = Pu[base9 + Nsz * 64];
        unsigned int u2 = Pu[base9 + 2 * Nsz * 64];
        acc00 += b * bf2f((unsigned short)u0); acc01 += b * bf2f((unsigned short)(u0 >> 16));
        acc10 += b * bf2f((unsigned short)u1); acc11 += b * bf2f((unsigned short)(u1 >> 16));
        acc20 += b * bf2f((unsigned short)u2); acc21 += b * bf2f((unsigned short)(u2 >> 16));
      }
    }
  }
  unsigned int* ho = (unsigned int*)hagg;
  ho[((size_t)0 * N + n) * 64 + lane] = ((unsigned int)f2bf(acc01) << 16) | f2bf(acc00);
  ho[((size_t)1 * N + n) * 64 + lane] = ((unsigned int)f2bf(acc11) << 16) | f2bf(acc10);
  ho[((size_t)2 * N + n) * 64 + lane] = ((unsigned int)f2bf(acc21) << 16) | f2bf(acc20);
}

// ---------------------------------------------------------------- output GEMM
__global__ __launch_bounds__(512) void k_out(
    const unsigned short* __restrict__ Hagg, const float* __restrict__ Wa,
    const float* __restrict__ ba,
    const float* __restrict__ x0, const float* __restrict__ x1,
    const float* __restrict__ x2, const float* __restrict__ skip,
    float* __restrict__ out, int N)
{
  __shared__ __attribute__((aligned(16))) unsigned short Wt[128 * 136];
  int m = blockIdx.y;
  const float* X = (m == 0) ? x0 : ((m == 1) ? x1 : x2);
  int tid = threadIdx.x;
#pragma unroll
  for (int it = 0; it < 8; it++) {        // 4096 float4 reads, 4 LDS stores each
    int idx = it * 512 + tid;
    int k = idx >> 5, c4 = (idx & 31) << 2;
    float4 w = *(const float4*)(&Wa[k * 128 + c4]);
    Wt[(c4 + 0) * 136 + k] = f2bf(w.x);
    Wt[(c4 + 1) * 136 + k] = f2bf(w.y);
    Wt[(c4 + 2) * 136 + k] = f2bf(w.z);
    Wt[(c4 + 3) * 136 + k] = f2bf(w.w);
  }
  __syncthreads();
  float alpha = 1.f / (1.f + __expf(-skip[0]));
  float oma = 1.f - alpha;
  int wave = tid >> 6, lane = tid & 63;
  int quad = lane >> 4, l16 = lane & 15;
  int row0 = blockIdx.x * 128 + wave * 16;
  int arow = row0 + l16; if (arow >= N) arow = N - 1;
  const unsigned short* hp = Hagg + ((size_t)m * N + arow) * D;
  floatx4 acc[8];
#pragma unroll
  for (int ct = 0; ct < 8; ct++) acc[ct] = (floatx4)0.f;
#pragma unroll
  for (int kk = 0; kk < 128; kk += 32) {
    uint4 au = *(const uint4*)(hp + kk + quad * 8);
    bf16x8 af = __builtin_bit_cast(bf16x8, au);
#pragma unroll
    for (int ct = 0; ct < 8; ct++) {
      uint4 bu = *(const uint4*)(&Wt[(ct * 16 + l16) * 136 + kk + quad * 8]);
      bf16x8 bf = __builtin_bit_cast(bf16x8, bu);
      acc[ct] = __builtin_amdgcn_mfma_f32_16x16x32_bf16(af, bf, acc[ct], 0, 0, 0);
    }
  }
  float* om = out + (size_t)m * N * D;
#pragma unroll
  for (int ct = 0; ct < 8; ct++) {
    int col = ct * 16 + l16;
    float bias = ba[col];
#pragma unroll
    for (int i = 0; i < 4; i++) {
      int r = row0 + quad * 4 + i;
      if (r < N) {
        om[(size_t)r * D + col] =
            (acc[ct][i] + bias) * alpha + X[(size_t)r * D + col] * oma;
      }
    }
  }
}

// ---------------------------------------------------------------- launch
extern "C" void kernel_launch(void* const* d_in, const int* in_sizes, int n_in,
                              void* d_out, int out_size, void* d_ws, size_t ws_size,
                              hipStream_t stream) {
  const float* x0 = (const float*)d_in[0];
  const float* x1 = (const float*)d_in[1];
  const float* x2 = (const float*)d_in[2];
  const float* Wk = (const float*)d_in[3];
  const float* bk = (const float*)d_in[4];
  const float* Wq = (const float*)d_in[5];
  const float* bq = (const float*)d_in[6];
  const float* Wv = (const float*)d_in[7];
  const float* bv = (const float*)d_in[8];
  const float* Wa = (const float*)d_in[9];
  const float* ba = (const float*)d_in[10];
  const float* rel_att = (const float*)d_in[11];
  const float* rel_msg = (const float*)d_in[12];
  const float* rel_pri = (const float*)d_in[13];
  const float* wm0 = (const float*)d_in[14];
  const float* wm1 = (const float*)d_in[15];
  const float* wm2 = (const float*)d_in[16];
  const float* skip = (const float*)d_in[17];
  const int* src = (const int*)d_in[18];
  const int* dstv = (const int*)d_in[19];
  int N = in_sizes[0] / D;      // 20000
  int E = in_sizes[18];         // 160000

  char* wsb = (char*)d_ws;
  size_t off = 0;
  auto alloc_b = [&](size_t bytes) { size_t o = off; off += (bytes + 63) & ~(size_t)63; return o; };
  unsigned short* P         = (unsigned short*)(wsb + alloc_b((size_t)12 * N * D * 2));
  unsigned short* Wt_all    = (unsigned short*)(wsb + alloc_b((size_t)6 * 16384 * 2));
  float*          bias_all  = (float*)(wsb + alloc_b((size_t)6 * 128 * 4));
  int*            cnt2      = (int*)(wsb + alloc_b(((size_t)2 * N + 64) * 4));  // counts|cursor|alloc
  int*            row_start = (int*)(wsb + alloc_b((size_t)(N + 1) * 4));
  int*            src_sorted= (int*)(wsb + alloc_b((size_t)E * 4));
  unsigned short* hagg      = (unsigned short*)(wsb + alloc_b((size_t)3 * N * D * 2));
  int* counts = cnt2;
  int* cursor = cnt2 + N;
  int* allocc = cnt2 + 2 * N;

  hipMemsetAsync(cnt2, 0, ((size_t)2 * N + 64) * sizeof(int), stream);
  int hist_blocks = (E + 255) / 256;
  k_misc<<<dim3(384 + hist_blocks), 256, 0, stream>>>(
      Wk, bk, Wq, bq, Wv, bv, rel_att, rel_msg, rel_pri, wm0, wm1, wm2,
      Wt_all, bias_all, dstv, counts, E);
  k_proj<<<dim3((N + 127) / 128, 4), 512, 0, stream>>>(
      x0, x1, x2, Wt_all, bias_all, P, counts, row_start, allocc, N);
  k_scatter<<<dim3((E + 255) / 256), 256, 0, stream>>>(
      dstv, src, row_start, cursor, src_sorted, E);
  k_node<<<dim3((N + 3) / 4), 256, 0, stream>>>(
      P, row_start, counts, src_sorted, hagg, N, E);
  k_out<<<dim3((N + 127) / 128, 3), 512, 0, stream>>>(
      hagg, Wa, ba, x0, x1, x2, skip, (float*)d_out, N);
}

// Round 8
// 255.528 us; speedup vs baseline: 1.0376x; 1.0376x over previous
//
#include <hip/hip_runtime.h>

#define D 128
#define NH 8

typedef __bf16 bf16x8 __attribute__((ext_vector_type(8)));
typedef unsigned short ushortx8 __attribute__((ext_vector_type(8)));
typedef float floatx4 __attribute__((ext_vector_type(4)));

__device__ __forceinline__ float bf2f(unsigned short u) {
  union { unsigned int i; float f; } x; x.i = ((unsigned int)u) << 16; return x.f;
}
__device__ __forceinline__ unsigned short f2bf(float f) {
  union { float f; unsigned int i; } x; x.f = f;
  unsigned int i = x.i;
  return (unsigned short)((i + 0x7FFFu + ((i >> 16) & 1u)) >> 16);
}
// accumulate both bf16 halves of packed uints into s
__device__ __forceinline__ void acc2(unsigned int ku, unsigned int qu, float& s) {
  union { unsigned int i; float f; } a, b;
  a.i = ku << 16;          b.i = qu << 16;          s += a.f * b.f;
  a.i = ku & 0xffff0000u;  b.i = qu & 0xffff0000u;  s += a.f * b.f;
}

// ---------------------------------------------------------------- transform + hist
// blocks [0,384): weight fold; blocks [384,...): dst histogram (counts pre-zeroed)
__global__ __launch_bounds__(256) void k_misc(
    const float* __restrict__ Wk, const float* __restrict__ bk,
    const float* __restrict__ Wq, const float* __restrict__ bq,
    const float* __restrict__ Wv, const float* __restrict__ bv,
    const float* __restrict__ rel_att, const float* __restrict__ rel_msg,
    const float* __restrict__ rel_pri,
    const float* __restrict__ wm0, const float* __restrict__ wm1,
    const float* __restrict__ wm2,
    unsigned short* __restrict__ Wt_all, float* __restrict__ bias_all,
    const int* __restrict__ dst, int* __restrict__ counts, int E)
{
  int b = blockIdx.x;
  if (b >= 384) {
    int e = (b - 384) * 256 + threadIdx.x;
    if (e < E) atomicAdd(&counts[dst[e]], 1);
    return;
  }
  int gid = b * 256 + threadIdx.x;
  if (gid >= 6 * 128 * 128) return;
  int p = gid >> 14;
  int idx = gid & 16383;
  int c = idx >> 7, k = idx & 127;
  int h = c >> 4, r = c & 15;
  float wsum = 0.f, bsum = 0.f;
  if (p == 0) {
    wsum = Wk[k * 128 + c];
    bsum = bk[c];
  } else if (p <= 4) {
    const float* M = (p == 1) ? rel_att : ((p == 2) ? wm0 : ((p == 3) ? wm1 : wm2));
#pragma unroll
    for (int f = 0; f < 16; f++) {
      float mv = M[h * 256 + r * 16 + f];
      wsum += Wq[k * 128 + h * 16 + f] * mv;
      bsum += bq[h * 16 + f] * mv;
    }
    if (p == 1) { float sc = rel_pri[h] * 2.5f; wsum *= sc; bsum *= sc; }
  } else {
#pragma unroll
    for (int d = 0; d < 16; d++) {
      float mv = rel_msg[h * 256 + d * 16 + r];
      wsum += Wv[k * 128 + h * 16 + d] * mv;
      bsum += bv[h * 16 + d] * mv;
    }
  }
  Wt_all[(size_t)p * 16384 + c * 128 + k] = f2bf(wsum);
  if (k == 0) bias_all[p * 128 + c] = bsum;
}

// ---------------------------------------------------------------- projections + assign
// grid (157, 4), 512 threads. y<3: 128-row GEMM tiles for modality y across the
// 4 weight planes. y==3,x==0: unordered CSR segment assignment via wave-scan +
// one atomicAdd per wave on a global allocator.
__global__ __launch_bounds__(512) void k_proj(
    const float* __restrict__ x0, const float* __restrict__ x1,
    const float* __restrict__ x2,
    const unsigned short* __restrict__ Wt_all, const float* __restrict__ bias_all,
    unsigned short* __restrict__ P,
    const int* __restrict__ counts, int* __restrict__ row_start,
    int* __restrict__ alloc, int N)
{
  if (blockIdx.y == 3) {
    if (blockIdx.x != 0) return;
    int tid = threadIdx.x, lane = tid & 63;
    for (int base = 0; base < N; base += 512) {
      int n = base + tid;
      int cnt = (n < N) ? counts[n] : 0;
      int x = cnt;
#pragma unroll
      for (int off = 1; off < 64; off <<= 1) {
        int y = __shfl_up(x, off, 64);
        if (lane >= off) x += y;
      }
      int wtot = __shfl(x, 63, 64);
      int wbase = 0;
      if (lane == 63) wbase = atomicAdd(alloc, wtot);
      wbase = __shfl(wbase, 63, 64);
      if (n < N) row_start[n] = wbase + x - cnt;
    }
    return;
  }
  __shared__ __attribute__((aligned(16))) unsigned short Wt[128 * 136];
  int m = blockIdx.y;
  const float* X = (m == 0) ? x0 : ((m == 1) ? x1 : x2);
  int tid = threadIdx.x;
  int wave = tid >> 6, lane = tid & 63;
  int quad = lane >> 4, l16 = lane & 15;
  int row0 = blockIdx.x * 128 + wave * 16;
  int arow = row0 + l16; if (arow >= N) arow = N - 1;
  const float* ap = X + (size_t)arow * D;
  bf16x8 afr[4];
#pragma unroll
  for (int kk4 = 0; kk4 < 4; kk4++) {
    float4 f0 = *(const float4*)(ap + kk4 * 32 + quad * 8);
    float4 f1 = *(const float4*)(ap + kk4 * 32 + quad * 8 + 4);
    ushortx8 uu;
    uu[0]=f2bf(f0.x); uu[1]=f2bf(f0.y); uu[2]=f2bf(f0.z); uu[3]=f2bf(f0.w);
    uu[4]=f2bf(f1.x); uu[5]=f2bf(f1.y); uu[6]=f2bf(f1.z); uu[7]=f2bf(f1.w);
    afr[kk4] = __builtin_bit_cast(bf16x8, uu);
  }
  for (int pt = 0; pt < 4; pt++) {
    int wp = (pt == 0) ? 0 : ((pt == 1) ? 1 : ((pt == 2) ? (2 + m) : 5));
    const unsigned short* Wsrc = Wt_all + (size_t)wp * 16384;
    const float* B = bias_all + wp * 128;
    __syncthreads();
#pragma unroll
    for (int it = 0; it < 4; it++) {              // 2048 uint4 = 32 KB
      int idx = it * 512 + tid;
      int c = idx >> 4, kc = (idx & 15) << 3;
      *(uint4*)(&Wt[c * 136 + kc]) = *(const uint4*)(&Wsrc[c * 128 + kc]);
    }
    __syncthreads();
    floatx4 acc[8];
#pragma unroll
    for (int ct = 0; ct < 8; ct++) acc[ct] = (floatx4)0.f;
#pragma unroll
    for (int kk4 = 0; kk4 < 4; kk4++) {
#pragma unroll
      for (int ct = 0; ct < 8; ct++) {
        uint4 bu = *(const uint4*)(&Wt[(ct * 16 + l16) * 136 + kk4 * 32 + quad * 8]);
        bf16x8 bf = __builtin_bit_cast(bf16x8, bu);
        acc[ct] = __builtin_amdgcn_mfma_f32_16x16x32_bf16(afr[kk4], bf, acc[ct], 0, 0, 0);
      }
    }
    unsigned short* Pout = P + (size_t)(pt * 3 + m) * N * D;
#pragma unroll
    for (int ct = 0; ct < 8; ct++) {
      int col = ct * 16 + l16;
      float bias = B[col];
#pragma unroll
      for (int i = 0; i < 4; i++) {
        int r = row0 + quad * 4 + i;
        if (r < N) Pout[(size_t)r * D + col] = f2bf(acc[ct][i] + bias);
      }
    }
  }
}

// ---------------------------------------------------------------- scatter src -> CSR
__global__ void k_scatter(const int* __restrict__ dst, const int* __restrict__ src,
                          const int* __restrict__ row_start,
                          int* __restrict__ cursor, int* __restrict__ src_sorted, int E) {
  int e = blockIdx.x * 256 + threadIdx.x;
  if (e < E) {
    int d = dst[e];
    int pos = atomicAdd(&cursor[d], 1);
    src_sorted[row_start[d] + pos] = src[e];
  }
}

// ---------------------------------------------------------------- fused node kernel
// q-slices in REGISTERS (round-6 form — LDS/minwaves variant spilled to scratch,
// 86us vs 63us; do not re-add __launch_bounds__ min-waves here).
__device__ __forceinline__ void edge_vals(
    const unsigned short* __restrict__ P, size_t Nsz, int s, int h,
    const uint4 (&qa)[3][2], const uint4 (&qw)[3][2],
    float (&av)[3], float (&lv)[3])
{
#pragma unroll
  for (int m = 0; m < 3; m++) {
    const unsigned short* kp = P + ((size_t)m * Nsz + s) * 128 + h * 16;
    uint4 k0 = *(const uint4*)kp, k1 = *(const uint4*)(kp + 8);
    const unsigned int* ka = (const unsigned int*)&k0;
    const unsigned int* kb = (const unsigned int*)&k1;
    const unsigned int* a0 = (const unsigned int*)&qa[m][0];
    const unsigned int* a1 = (const unsigned int*)&qa[m][1];
    const unsigned int* w0 = (const unsigned int*)&qw[m][0];
    const unsigned int* w1 = (const unsigned int*)&qw[m][1];
    float da = 0.f, dw = 0.f;
#pragma unroll
    for (int j = 0; j < 4; j++) {
      acc2(ka[j], a0[j], da); acc2(kb[j], a1[j], da);
      acc2(ka[j], w0[j], dw); acc2(kb[j], w1[j], dw);
    }
    av[m] = da;          // rel_pri*2.5 folded into QA plane
    lv[m] = dw;
  }
  float mx = fmaxf(lv[0], fmaxf(lv[1], lv[2]));
  float e0 = __expf(lv[0] - mx), e1 = __expf(lv[1] - mx), e2 = __expf(lv[2] - mx);
  float inv = 1.f / (e0 + e1 + e2);
  lv[0] = e0 * inv; lv[1] = e1 * inv; lv[2] = e2 * inv;
}

// one wave per dst node; 4-chunk register cache (deg<=32 fast path).
__global__ __launch_bounds__(256) void k_node(
    const unsigned short* __restrict__ P,
    const int* __restrict__ row_start, const int* __restrict__ counts,
    const int* __restrict__ srcs,
    unsigned short* __restrict__ hagg, int N, int E)
{
  int tid = threadIdx.x;
  int wave = tid >> 6, lane = tid & 63;
  int n = blockIdx.x * 4 + wave;
  if (n >= N) return;
  int ro = row_start[n];
  int deg = counts[n];
  float acc00 = 0, acc01 = 0, acc10 = 0, acc11 = 0, acc20 = 0, acc21 = 0;
  if (deg > 0) {
    int h = lane & 7, slot = lane >> 3;
    size_t Nsz = (size_t)N;
    uint4 qa[3][2], qw[3][2];
#pragma unroll
    for (int m = 0; m < 3; m++) {
      const unsigned short* qap = P + ((size_t)(3 + m) * Nsz + n) * 128 + h * 16;
      const unsigned short* qwp = P + ((size_t)(6 + m) * Nsz + n) * 128 + h * 16;
      qa[m][0] = *(const uint4*)qap; qa[m][1] = *(const uint4*)(qap + 8);
      qw[m][0] = *(const uint4*)qwp; qw[m][1] = *(const uint4*)(qwp + 8);
    }
    int nch = (deg + 7) >> 3;
    float cX0[4] = {}, cX1[4] = {}, cX2[4] = {}, cEa[4] = {}, cT[4] = {};
    int cS[4] = {};
    // ---- phase 1: sumA_m, sumAl
    float sA0 = 0, sA1 = 0, sA2 = 0, sAl = 0;
#pragma unroll
    for (int c = 0; c < 4; c++) {
      int idx = c * 8 + slot;
      if (c < nch && idx < deg) {
        int s = srcs[ro + idx]; cS[c] = s;
        float av[3], lv[3];
        edge_vals(P, Nsz, s, h, qa, qw, av, lv);
        float e0 = __expf(av[0]), e1 = __expf(av[1]), e2 = __expf(av[2]);
        float align = -(fabsf(av[0]-av[1]) + fabsf(av[0]-av[2]) + fabsf(av[1]-av[2])) * (1.f/3.f);
        float ea = __expf(align);
        cX0[c] = lv[0] * e0; cX1[c] = lv[1] * e1; cX2[c] = lv[2] * e2; cEa[c] = ea;
        sA0 += e0; sA1 += e1; sA2 += e2; sAl += ea;
      }
    }
    for (int c = 4; c < nch; c++) {          // rare deg>32 fallback
      int idx = c * 8 + slot;
      if (idx < deg) {
        int s = srcs[ro + idx];
        float av[3], lv[3];
        edge_vals(P, Nsz, s, h, qa, qw, av, lv);
        float align = -(fabsf(av[0]-av[1]) + fabsf(av[0]-av[2]) + fabsf(av[1]-av[2])) * (1.f/3.f);
        sA0 += __expf(av[0]); sA1 += __expf(av[1]); sA2 += __expf(av[2]);
        sAl += __expf(align);
      }
    }
#pragma unroll
    for (int off = 8; off < 64; off <<= 1) {
      sA0 += __shfl_xor(sA0, off, 64);
      sA1 += __shfl_xor(sA1, off, 64);
      sA2 += __shfl_xor(sA2, off, 64);
      sAl += __shfl_xor(sAl, off, 64);
    }
    float rA0 = 1.f / fmaxf(sA0, 1e-30f), rA1 = 1.f / fmaxf(sA1, 1e-30f);
    float rA2 = 1.f / fmaxf(sA2, 1e-30f), rAl = 1.f / fmaxf(sAl, 1e-30f);
    // ---- phase 2: sumT
    float sT = 0;
#pragma unroll
    for (int c = 0; c < 4; c++) {
      int idx = c * 8 + slot;
      if (c < nch && idx < deg) {
        float t = (cX0[c] * rA0 + cX1[c] * rA1 + cX2[c] * rA2) * (cEa[c] * rAl);
        cT[c] = t;
        sT += __expf(t);
      }
    }
    for (int c = 4; c < nch; c++) {
      int idx = c * 8 + slot;
      if (idx < deg) {
        int s = srcs[ro + idx];
        float av[3], lv[3];
        edge_vals(P, Nsz, s, h, qa, qw, av, lv);
        float align = -(fabsf(av[0]-av[1]) + fabsf(av[0]-av[2]) + fabsf(av[1]-av[2])) * (1.f/3.f);
        float t = (lv[0]*__expf(av[0])*rA0 + lv[1]*__expf(av[1])*rA1 + lv[2]*__expf(av[2])*rA2)
                  * (__expf(align) * rAl);
        sT += __expf(t);
      }
    }
#pragma unroll
    for (int off = 8; off < 64; off <<= 1) sT += __shfl_xor(sT, off, 64);
    float rT = 1.f / fmaxf(sT, 1e-30f);
    // ---- phase 3: beta + aggregation, fully unrolled + predicated
    const unsigned int* Pu = (const unsigned int*)P;
    int hl = lane >> 3;
#pragma unroll
    for (int c = 0; c < 4; c++) {
      if (c < nch) {
        int idx = c * 8 + slot;
        float beta = (idx < deg) ? __expf(cT[c]) * rT : 0.f;
        int sv = cS[c];          // 0 for invalid slots (cached node-0 row, b=0)
        float bj[8]; int sj[8];
#pragma unroll
        for (int jj = 0; jj < 8; jj++) {
          bj[jj] = __shfl(beta, jj * 8 + hl, 64);
          sj[jj] = __shfl(sv, jj * 8, 64);
        }
#pragma unroll
        for (int jj = 0; jj < 8; jj++) {
          size_t base9 = ((size_t)9 * Nsz + sj[jj]) * 64 + lane;
          unsigned int u0 = Pu[base9];
          unsigned int u1 = Pu[base9 + Nsz * 64];
          unsigned int u2 = Pu[base9 + 2 * Nsz * 64];
          float b = bj[jj];
          acc00 += b * bf2f((unsigned short)u0); acc01 += b * bf2f((unsigned short)(u0 >> 16));
          acc10 += b * bf2f((unsigned short)u1); acc11 += b * bf2f((unsigned short)(u1 >> 16));
          acc20 += b * bf2f((unsigned short)u2); acc21 += b * bf2f((unsigned short)(u2 >> 16));
        }
      }
    }
    for (int c = 4; c < nch; c++) {          // rare deg>32 fallback
      int idx = c * 8 + slot;
      float beta = 0.f; int sv = 0;
      if (idx < deg) {
        sv = srcs[ro + idx];
        float av[3], lv[3];
        edge_vals(P, Nsz, sv, h, qa, qw, av, lv);
        float align = -(fabsf(av[0]-av[1]) + fabsf(av[0]-av[2]) + fabsf(av[1]-av[2])) * (1.f/3.f);
        float t = (lv[0]*__expf(av[0])*rA0 + lv[1]*__expf(av[1])*rA1 + lv[2]*__expf(av[2])*rA2)
                  * (__expf(align) * rAl);
        beta = __expf(t) * rT;
      }
      int jmax = min(8, deg - c * 8);
      for (int jj = 0; jj < jmax; jj++) {
        float b = __shfl(beta, jj * 8 + hl, 64);
        int s = __shfl(sv, jj * 8, 64);
        size_t base9 = ((size_t)9 * Nsz + s) * 64 + lane;
        unsigned int u0 = Pu[base9];
        unsigned int u1 = Pu[base9 + Nsz * 64];
        unsigned int u2 = Pu[base9 + 2 * Nsz * 64];
        acc00 += b * bf2f((unsigned short)u0); acc01 += b * bf2f((unsigned short)(u0 >> 16));
        acc10 += b * bf2f((unsigned short)u1); acc11 += b * bf2f((unsigned short)(u1 >> 16));
        acc20 += b * bf2f((unsigned short)u2); acc21 += b * bf2f((unsigned short)(u2 >> 16));
      }
    }
  }
  unsigned int* ho = (unsigned int*)hagg;
  ho[((size_t)0 * N + n) * 64 + lane] = ((unsigned int)f2bf(acc01) << 16) | f2bf(acc00);
  ho[((size_t)1 * N + n) * 64 + lane] = ((unsigned int)f2bf(acc11) << 16) | f2bf(acc10);
  ho[((size_t)2 * N + n) * 64 + lane] = ((unsigned int)f2bf(acc21) << 16) | f2bf(acc20);
}

// ---------------------------------------------------------------- output GEMM
__global__ __launch_bounds__(512) void k_out(
    const unsigned short* __restrict__ Hagg, const float* __restrict__ Wa,
    const float* __restrict__ ba,
    const float* __restrict__ x0, const float* __restrict__ x1,
    const float* __restrict__ x2, const float* __restrict__ skip,
    float* __restrict__ out, int N)
{
  __shared__ __attribute__((aligned(16))) unsigned short Wt[128 * 136];
  int m = blockIdx.y;
  const float* X = (m == 0) ? x0 : ((m == 1) ? x1 : x2);
  int tid = threadIdx.x;
#pragma unroll
  for (int it = 0; it < 8; it++) {
    int idx = it * 512 + tid;
    int k = idx >> 5, c4 = (idx & 31) << 2;
    float4 w = *(const float4*)(&Wa[k * 128 + c4]);
    Wt[(c4 + 0) * 136 + k] = f2bf(w.x);
    Wt[(c4 + 1) * 136 + k] = f2bf(w.y);
    Wt[(c4 + 2) * 136 + k] = f2bf(w.z);
    Wt[(c4 + 3) * 136 + k] = f2bf(w.w);
  }
  __syncthreads();
  float alpha = 1.f / (1.f + __expf(-skip[0]));
  float oma = 1.f - alpha;
  int wave = tid >> 6, lane = tid & 63;
  int quad = lane >> 4, l16 = lane & 15;
  int row0 = blockIdx.x * 128 + wave * 16;
  int arow = row0 + l16; if (arow >= N) arow = N - 1;
  const unsigned short* hp = Hagg + ((size_t)m * N + arow) * D;
  floatx4 acc[8];
#pragma unroll
  for (int ct = 0; ct < 8; ct++) acc[ct] = (floatx4)0.f;
#pragma unroll
  for (int kk = 0; kk < 128; kk += 32) {
    uint4 au = *(const uint4*)(hp + kk + quad * 8);
    bf16x8 af = __builtin_bit_cast(bf16x8, au);
#pragma unroll
    for (int ct = 0; ct < 8; ct++) {
      uint4 bu = *(const uint4*)(&Wt[(ct * 16 + l16) * 136 + kk + quad * 8]);
      bf16x8 bf = __builtin_bit_cast(bf16x8, bu);
      acc[ct] = __builtin_amdgcn_mfma_f32_16x16x32_bf16(af, bf, acc[ct], 0, 0, 0);
    }
  }
  float* om = out + (size_t)m * N * D;
#pragma unroll
  for (int ct = 0; ct < 8; ct++) {
    int col = ct * 16 + l16;
    float bias = ba[col];
#pragma unroll
    for (int i = 0; i < 4; i++) {
      int r = row0 + quad * 4 + i;
      if (r < N) {
        om[(size_t)r * D + col] =
            (acc[ct][i] + bias) * alpha + X[(size_t)r * D + col] * oma;
      }
    }
  }
}

// ---------------------------------------------------------------- launch
extern "C" void kernel_launch(void* const* d_in, const int* in_sizes, int n_in,
                              void* d_out, int out_size, void* d_ws, size_t ws_size,
                              hipStream_t stream) {
  const float* x0 = (const float*)d_in[0];
  const float* x1 = (const float*)d_in[1];
  const float* x2 = (const float*)d_in[2];
  const float* Wk = (const float*)d_in[3];
  const float* bk = (const float*)d_in[4];
  const float* Wq = (const float*)d_in[5];
  const float* bq = (const float*)d_in[6];
  const float* Wv = (const float*)d_in[7];
  const float* bv = (const float*)d_in[8];
  const float* Wa = (const float*)d_in[9];
  const float* ba = (const float*)d_in[10];
  const float* rel_att = (const float*)d_in[11];
  const float* rel_msg = (const float*)d_in[12];
  const float* rel_pri = (const float*)d_in[13];
  const float* wm0 = (const float*)d_in[14];
  const float* wm1 = (const float*)d_in[15];
  const float* wm2 = (const float*)d_in[16];
  const float* skip = (const float*)d_in[17];
  const int* src = (const int*)d_in[18];
  const int* dstv = (const int*)d_in[19];
  int N = in_sizes[0] / D;      // 20000
  int E = in_sizes[18];         // 160000

  char* wsb = (char*)d_ws;
  size_t off = 0;
  auto alloc_b = [&](size_t bytes) { size_t o = off; off += (bytes + 63) & ~(size_t)63; return o; };
  unsigned short* P         = (unsigned short*)(wsb + alloc_b((size_t)12 * N * D * 2));
  unsigned short* Wt_all    = (unsigned short*)(wsb + alloc_b((size_t)6 * 16384 * 2));
  float*          bias_all  = (float*)(wsb + alloc_b((size_t)6 * 128 * 4));
  int*            cnt2      = (int*)(wsb + alloc_b(((size_t)2 * N + 64) * 4));  // counts|cursor|alloc
  int*            row_start = (int*)(wsb + alloc_b((size_t)(N + 1) * 4));
  int*            src_sorted= (int*)(wsb + alloc_b((size_t)E * 4));
  unsigned short* hagg      = (unsigned short*)(wsb + alloc_b((size_t)3 * N * D * 2));
  int* counts = cnt2;
  int* cursor = cnt2 + N;
  int* allocc = cnt2 + 2 * N;

  hipMemsetAsync(cnt2, 0, ((size_t)2 * N + 64) * sizeof(int), stream);
  int hist_blocks = (E + 255) / 256;
  k_misc<<<dim3(384 + hist_blocks), 256, 0, stream>>>(
      Wk, bk, Wq, bq, Wv, bv, rel_att, rel_msg, rel_pri, wm0, wm1, wm2,
      Wt_all, bias_all, dstv, counts, E);
  k_proj<<<dim3((N + 127) / 128, 4), 512, 0, stream>>>(
      x0, x1, x2, Wt_all, bias_all, P, counts, row_start, allocc, N);
  k_scatter<<<dim3((E + 255) / 256), 256, 0, stream>>>(
      dstv, src, row_start, cursor, src_sorted, E);
  k_node<<<dim3((N + 3) / 4), 256, 0, stream>>>(
      P, row_start, counts, src_sorted, hagg, N, E);
  k_out<<<dim3((N + 127) / 128, 3), 512, 0, stream>>>(
      hagg, Wa, ba, x0, x1, x2, skip, (float*)d_out, N);
}

// Round 9
// 248.833 us; speedup vs baseline: 1.0655x; 1.0269x over previous
//
#include <hip/hip_runtime.h>

#define D 128
#define NH 8

typedef __bf16 bf16x8 __attribute__((ext_vector_type(8)));
typedef unsigned short ushortx8 __attribute__((ext_vector_type(8)));
typedef float floatx4 __attribute__((ext_vector_type(4)));

__device__ __forceinline__ float bf2f(unsigned short u) {
  union { unsigned int i; float f; } x; x.i = ((unsigned int)u) << 16; return x.f;
}
__device__ __forceinline__ unsigned short f2bf(float f) {
  union { float f; unsigned int i; } x; x.f = f;
  unsigned int i = x.i;
  return (unsigned short)((i + 0x7FFFu + ((i >> 16) & 1u)) >> 16);
}
__device__ __forceinline__ void acc2(unsigned int ku, unsigned int qu, float& s) {
  union { unsigned int i; float f; } a, b;
  a.i = ku << 16;          b.i = qu << 16;          s += a.f * b.f;
  a.i = ku & 0xffff0000u;  b.i = qu & 0xffff0000u;  s += a.f * b.f;
}

// =============== device-scope grid barrier (persistent-kernel pattern) ======
// release add + acquire spin; separate cache line per phase; counters zeroed
// by the per-launch memset. All blocks co-resident (grid sized via occupancy).
__device__ __forceinline__ void gbar(int* cnt, int nb) {
  __threadfence();                       // release this thread's writes
  __syncthreads();
  if (threadIdx.x == 0) {
    __hip_atomic_fetch_add(cnt, 1, __ATOMIC_ACQ_REL, __HIP_MEMORY_SCOPE_AGENT);
    while (__hip_atomic_load(cnt, __ATOMIC_ACQUIRE, __HIP_MEMORY_SCOPE_AGENT) < nb) {}
  }
  __syncthreads();
  __threadfence();                       // acquire: see other blocks' writes
}

// =============== phase helpers (proven bodies from rounds 6/8) ==============
// weight fold: p0 Wk ; p1 Wq.rel_attT * pri*2.5 ; p2..4 Wq.wm_mT ; p5 Wv.rel_msg
__device__ __forceinline__ void fold_item(
    int gid,
    const float* __restrict__ Wk, const float* __restrict__ bk,
    const float* __restrict__ Wq, const float* __restrict__ bq,
    const float* __restrict__ Wv, const float* __restrict__ bv,
    const float* __restrict__ rel_att, const float* __restrict__ rel_msg,
    const float* __restrict__ rel_pri,
    const float* __restrict__ wm0, const float* __restrict__ wm1,
    const float* __restrict__ wm2,
    unsigned short* __restrict__ Wt_all, float* __restrict__ bias_all)
{
  int p = gid >> 14;
  int idx = gid & 16383;
  int c = idx >> 7, k = idx & 127;
  int h = c >> 4, r = c & 15;
  float wsum = 0.f, bsum = 0.f;
  if (p == 0) {
    wsum = Wk[k * 128 + c];
    bsum = bk[c];
  } else if (p <= 4) {
    const float* M = (p == 1) ? rel_att : ((p == 2) ? wm0 : ((p == 3) ? wm1 : wm2));
#pragma unroll
    for (int f = 0; f < 16; f++) {
      float mv = M[h * 256 + r * 16 + f];
      wsum += Wq[k * 128 + h * 16 + f] * mv;
      bsum += bq[h * 16 + f] * mv;
    }
    if (p == 1) { float sc = rel_pri[h] * 2.5f; wsum *= sc; bsum *= sc; }
  } else {
#pragma unroll
    for (int d = 0; d < 16; d++) {
      float mv = rel_msg[h * 256 + d * 16 + r];
      wsum += Wv[k * 128 + h * 16 + d] * mv;
      bsum += bv[h * 16 + d] * mv;
    }
  }
  Wt_all[(size_t)p * 16384 + c * 128 + k] = f2bf(wsum);
  if (k == 0) bias_all[p * 128 + c] = bsum;
}

// one 64-row x 4-plane projection tile, 256 threads (round-6 body)
__device__ __forceinline__ void proj_tile(
    int t, const float* __restrict__ x0, const float* __restrict__ x1,
    const float* __restrict__ x2,
    const unsigned short* __restrict__ Wt_all, const float* __restrict__ bias_all,
    unsigned short* __restrict__ P, int N, unsigned short* Wt, int tid)
{
  int m = t % 3, rt = t / 3;
  const float* X = (m == 0) ? x0 : ((m == 1) ? x1 : x2);
  int wave = tid >> 6, lane = tid & 63;
  int quad = lane >> 4, l16 = lane & 15;
  int row0 = rt * 64 + wave * 16;
  int arow = row0 + l16; if (arow >= N) arow = N - 1;
  const float* ap = X + (size_t)arow * D;
  bf16x8 afr[4];
#pragma unroll
  for (int kk4 = 0; kk4 < 4; kk4++) {
    float4 f0 = *(const float4*)(ap + kk4 * 32 + quad * 8);
    float4 f1 = *(const float4*)(ap + kk4 * 32 + quad * 8 + 4);
    ushortx8 uu;
    uu[0]=f2bf(f0.x); uu[1]=f2bf(f0.y); uu[2]=f2bf(f0.z); uu[3]=f2bf(f0.w);
    uu[4]=f2bf(f1.x); uu[5]=f2bf(f1.y); uu[6]=f2bf(f1.z); uu[7]=f2bf(f1.w);
    afr[kk4] = __builtin_bit_cast(bf16x8, uu);
  }
  for (int pt = 0; pt < 4; pt++) {
    int wp = (pt == 0) ? 0 : ((pt == 1) ? 1 : ((pt == 2) ? (2 + m) : 5));
    const unsigned short* Wsrc = Wt_all + (size_t)wp * 16384;
    const float* B = bias_all + wp * 128;
    __syncthreads();
#pragma unroll
    for (int it = 0; it < 8; it++) {
      int idx = it * 256 + tid;
      int c = idx >> 4, kc = (idx & 15) << 3;
      *(uint4*)(&Wt[c * 136 + kc]) = *(const uint4*)(&Wsrc[c * 128 + kc]);
    }
    __syncthreads();
    floatx4 acc[8];
#pragma unroll
    for (int ct = 0; ct < 8; ct++) acc[ct] = (floatx4)0.f;
#pragma unroll
    for (int kk4 = 0; kk4 < 4; kk4++) {
#pragma unroll
      for (int ct = 0; ct < 8; ct++) {
        uint4 bu = *(const uint4*)(&Wt[(ct * 16 + l16) * 136 + kk4 * 32 + quad * 8]);
        bf16x8 bf = __builtin_bit_cast(bf16x8, bu);
        acc[ct] = __builtin_amdgcn_mfma_f32_16x16x32_bf16(afr[kk4], bf, acc[ct], 0, 0, 0);
      }
    }
    unsigned short* Pout = P + (size_t)(pt * 3 + m) * N * D;
#pragma unroll
    for (int ct = 0; ct < 8; ct++) {
      int col = ct * 16 + l16;
      float bias = B[col];
#pragma unroll
      for (int i = 0; i < 4; i++) {
        int r = row0 + quad * 4 + i;
        if (r < N) Pout[(size_t)r * D + col] = f2bf(acc[ct][i] + bias);
      }
    }
  }
}

// unordered CSR segment assignment: one wave handles 64 nodes, one atomicAdd
__device__ __forceinline__ void assign_chunk(
    int a, const int* __restrict__ counts, int* __restrict__ row_start,
    int* __restrict__ cursor, int* __restrict__ allocg, int N, int lane)
{
  int n = a * 64 + lane;
  int cnt = (n < N) ? counts[n] : 0;
  int x = cnt;
#pragma unroll
  for (int off = 1; off < 64; off <<= 1) {
    int y = __shfl_up(x, off, 64);
    if (lane >= off) x += y;
  }
  int wtot = __shfl(x, 63, 64);
  int wbase = 0;
  if (lane == 63) wbase = atomicAdd(allocg, wtot);
  wbase = __shfl(wbase, 63, 64);
  if (n < N) { int v = wbase + x - cnt; row_start[n] = v; cursor[n] = v; }
}

// one dst node per wave — round-8 body verbatim (register q-caches; the
// LDS/min-waves variant spilled to scratch: 86us vs 63us — keep registers).
__device__ __forceinline__ void edge_vals(
    const unsigned short* __restrict__ P, size_t Nsz, int s, int h,
    const uint4 (&qa)[3][2], const uint4 (&qw)[3][2],
    float (&av)[3], float (&lv)[3])
{
#pragma unroll
  for (int m = 0; m < 3; m++) {
    const unsigned short* kp = P + ((size_t)m * Nsz + s) * 128 + h * 16;
    uint4 k0 = *(const uint4*)kp, k1 = *(const uint4*)(kp + 8);
    const unsigned int* ka = (const unsigned int*)&k0;
    const unsigned int* kb = (const unsigned int*)&k1;
    const unsigned int* a0 = (const unsigned int*)&qa[m][0];
    const unsigned int* a1 = (const unsigned int*)&qa[m][1];
    const unsigned int* w0 = (const unsigned int*)&qw[m][0];
    const unsigned int* w1 = (const unsigned int*)&qw[m][1];
    float da = 0.f, dw = 0.f;
#pragma unroll
    for (int j = 0; j < 4; j++) {
      acc2(ka[j], a0[j], da); acc2(kb[j], a1[j], da);
      acc2(ka[j], w0[j], dw); acc2(kb[j], w1[j], dw);
    }
    av[m] = da;
    lv[m] = dw;
  }
  float mx = fmaxf(lv[0], fmaxf(lv[1], lv[2]));
  float e0 = __expf(lv[0] - mx), e1 = __expf(lv[1] - mx), e2 = __expf(lv[2] - mx);
  float inv = 1.f / (e0 + e1 + e2);
  lv[0] = e0 * inv; lv[1] = e1 * inv; lv[2] = e2 * inv;
}

__device__ __forceinline__ void node_one(
    int n, const unsigned short* __restrict__ P,
    const int* __restrict__ row_start, const int* __restrict__ counts,
    const int* __restrict__ srcs, unsigned short* __restrict__ hagg,
    int N, int lane)
{
  int ro = row_start[n];
  int deg = counts[n];
  float acc00 = 0, acc01 = 0, acc10 = 0, acc11 = 0, acc20 = 0, acc21 = 0;
  if (deg > 0) {
    int h = lane & 7, slot = lane >> 3;
    size_t Nsz = (size_t)N;
    uint4 qa[3][2], qw[3][2];
#pragma unroll
    for (int m = 0; m < 3; m++) {
      const unsigned short* qap = P + ((size_t)(3 + m) * Nsz + n) * 128 + h * 16;
      const unsigned short* qwp = P + ((size_t)(6 + m) * Nsz + n) * 128 + h * 16;
      qa[m][0] = *(const uint4*)qap; qa[m][1] = *(const uint4*)(qap + 8);
      qw[m][0] = *(const uint4*)qwp; qw[m][1] = *(const uint4*)(qwp + 8);
    }
    int nch = (deg + 7) >> 3;
    float cX0[4] = {}, cX1[4] = {}, cX2[4] = {}, cEa[4] = {}, cT[4] = {};
    int cS[4] = {};
    float sA0 = 0, sA1 = 0, sA2 = 0, sAl = 0;
#pragma unroll
    for (int c = 0; c < 4; c++) {
      int idx = c * 8 + slot;
      if (c < nch && idx < deg) {
        int s = srcs[ro + idx]; cS[c] = s;
        float av[3], lv[3];
        edge_vals(P, Nsz, s, h, qa, qw, av, lv);
        float e0 = __expf(av[0]), e1 = __expf(av[1]), e2 = __expf(av[2]);
        float align = -(fabsf(av[0]-av[1]) + fabsf(av[0]-av[2]) + fabsf(av[1]-av[2])) * (1.f/3.f);
        float ea = __expf(align);
        cX0[c] = lv[0] * e0; cX1[c] = lv[1] * e1; cX2[c] = lv[2] * e2; cEa[c] = ea;
        sA0 += e0; sA1 += e1; sA2 += e2; sAl += ea;
      }
    }
    for (int c = 4; c < nch; c++) {
      int idx = c * 8 + slot;
      if (idx < deg) {
        int s = srcs[ro + idx];
        float av[3], lv[3];
        edge_vals(P, Nsz, s, h, qa, qw, av, lv);
        float align = -(fabsf(av[0]-av[1]) + fabsf(av[0]-av[2]) + fabsf(av[1]-av[2])) * (1.f/3.f);
        sA0 += __expf(av[0]); sA1 += __expf(av[1]); sA2 += __expf(av[2]);
        sAl += __expf(align);
      }
    }
#pragma unroll
    for (int off = 8; off < 64; off <<= 1) {
      sA0 += __shfl_xor(sA0, off, 64);
      sA1 += __shfl_xor(sA1, off, 64);
      sA2 += __shfl_xor(sA2, off, 64);
      sAl += __shfl_xor(sAl, off, 64);
    }
    float rA0 = 1.f / fmaxf(sA0, 1e-30f), rA1 = 1.f / fmaxf(sA1, 1e-30f);
    float rA2 = 1.f / fmaxf(sA2, 1e-30f), rAl = 1.f / fmaxf(sAl, 1e-30f);
    float sT = 0;
#pragma unroll
    for (int c = 0; c < 4; c++) {
      int idx = c * 8 + slot;
      if (c < nch && idx < deg) {
        float t = (cX0[c] * rA0 + cX1[c] * rA1 + cX2[c] * rA2) * (cEa[c] * rAl);
        cT[c] = t;
        sT += __expf(t);
      }
    }
    for (int c = 4; c < nch; c++) {
      int idx = c * 8 + slot;
      if (idx < deg) {
        int s = srcs[ro + idx];
        float av[3], lv[3];
        edge_vals(P, Nsz, s, h, qa, qw, av, lv);
        float align = -(fabsf(av[0]-av[1]) + fabsf(av[0]-av[2]) + fabsf(av[1]-av[2])) * (1.f/3.f);
        float t = (lv[0]*__expf(av[0])*rA0 + lv[1]*__expf(av[1])*rA1 + lv[2]*__expf(av[2])*rA2)
                  * (__expf(align) * rAl);
        sT += __expf(t);
      }
    }
#pragma unroll
    for (int off = 8; off < 64; off <<= 1) sT += __shfl_xor(sT, off, 64);
    float rT = 1.f / fmaxf(sT, 1e-30f);
    const unsigned int* Pu = (const unsigned int*)P;
    int hl = lane >> 3;
#pragma unroll
    for (int c = 0; c < 4; c++) {
      if (c < nch) {
        int idx = c * 8 + slot;
        float beta = (idx < deg) ? __expf(cT[c]) * rT : 0.f;
        int sv = cS[c];
        float bj[8]; int sj[8];
#pragma unroll
        for (int jj = 0; jj < 8; jj++) {
          bj[jj] = __shfl(beta, jj * 8 + hl, 64);
          sj[jj] = __shfl(sv, jj * 8, 64);
        }
#pragma unroll
        for (int jj = 0; jj < 8; jj++) {
          size_t base9 = ((size_t)9 * Nsz + sj[jj]) * 64 + lane;
          unsigned int u0 = Pu[base9];
          unsigned int u1 = Pu[base9 + Nsz * 64];
          unsigned int u2 = Pu[base9 + 2 * Nsz * 64];
          float b = bj[jj];
          acc00 += b * bf2f((unsigned short)u0); acc01 += b * bf2f((unsigned short)(u0 >> 16));
          acc10 += b * bf2f((unsigned short)u1); acc11 += b * bf2f((unsigned short)(u1 >> 16));
          acc20 += b * bf2f((unsigned short)u2); acc21 += b * bf2f((unsigned short)(u2 >> 16));
        }
      }
    }
    for (int c = 4; c < nch; c++) {
      int idx = c * 8 + slot;
      float beta = 0.f; int sv = 0;
      if (idx < deg) {
        sv = srcs[ro + idx];
        float av[3], lv[3];
        edge_vals(P, Nsz, sv, h, qa, qw, av, lv);
        float align = -(fabsf(av[0]-av[1]) + fabsf(av[0]-av[2]) + fabsf(av[1]-av[2])) * (1.f/3.f);
        float t = (lv[0]*__expf(av[0])*rA0 + lv[1]*__expf(av[1])*rA1 + lv[2]*__expf(av[2])*rA2)
                  * (__expf(align) * rAl);
        beta = __expf(t) * rT;
      }
      int jmax = min(8, deg - c * 8);
      for (int jj = 0; jj < jmax; jj++) {
        float b = __shfl(beta, jj * 8 + hl, 64);
        int s = __shfl(sv, jj * 8, 64);
        size_t base9 = ((size_t)9 * Nsz + s) * 64 + lane;
        unsigned int u0 = Pu[base9];
        unsigned int u1 = Pu[base9 + Nsz * 64];
        unsigned int u2 = Pu[base9 + 2 * Nsz * 64];
        acc00 += b * bf2f((unsigned short)u0); acc01 += b * bf2f((unsigned short)(u0 >> 16));
        acc10 += b * bf2f((unsigned short)u1); acc11 += b * bf2f((unsigned short)(u1 >> 16));
        acc20 += b * bf2f((unsigned short)u2); acc21 += b * bf2f((unsigned short)(u2 >> 16));
      }
    }
  }
  unsigned int* ho = (unsigned int*)hagg;
  ho[((size_t)0 * N + n) * 64 + lane] = ((unsigned int)f2bf(acc01) << 16) | f2bf(acc00);
  ho[((size_t)1 * N + n) * 64 + lane] = ((unsigned int)f2bf(acc11) << 16) | f2bf(acc10);
  ho[((size_t)2 * N + n) * 64 + lane] = ((unsigned int)f2bf(acc21) << 16) | f2bf(acc20);
}

// one 64-row output tile, 256 threads; Wa pre-staged in Wt
__device__ __forceinline__ void out_tile(
    int t, const unsigned short* __restrict__ Hagg, const float* __restrict__ ba,
    const float* __restrict__ x0, const float* __restrict__ x1,
    const float* __restrict__ x2, float alpha,
    float* __restrict__ out, int N, const unsigned short* Wt, int tid)
{
  int m = t % 3, rt = t / 3;
  const float* X = (m == 0) ? x0 : ((m == 1) ? x1 : x2);
  float oma = 1.f - alpha;
  int wave = tid >> 6, lane = tid & 63;
  int quad = lane >> 4, l16 = lane & 15;
  int row0 = rt * 64 + wave * 16;
  int arow = row0 + l16; if (arow >= N) arow = N - 1;
  const unsigned short* hp = Hagg + ((size_t)m * N + arow) * D;
  floatx4 acc[8];
#pragma unroll
  for (int ct = 0; ct < 8; ct++) acc[ct] = (floatx4)0.f;
#pragma unroll
  for (int kk = 0; kk < 128; kk += 32) {
    uint4 au = *(const uint4*)(hp + kk + quad * 8);
    bf16x8 af = __builtin_bit_cast(bf16x8, au);
#pragma unroll
    for (int ct = 0; ct < 8; ct++) {
      uint4 bu = *(const uint4*)(&Wt[(ct * 16 + l16) * 136 + kk + quad * 8]);
      bf16x8 bf = __builtin_bit_cast(bf16x8, bu);
      acc[ct] = __builtin_amdgcn_mfma_f32_16x16x32_bf16(af, bf, acc[ct], 0, 0, 0);
    }
  }
  float* om = out + (size_t)m * N * D;
#pragma unroll
  for (int ct = 0; ct < 8; ct++) {
    int col = ct * 16 + l16;
    float bias = ba[col];
#pragma unroll
    for (int i = 0; i < 4; i++) {
      int r = row0 + quad * 4 + i;
      if (r < N) {
        om[(size_t)r * D + col] =
            (acc[ct][i] + bias) * alpha + X[(size_t)r * D + col] * oma;
      }
    }
  }
}

// =============== persistent mega-kernel (single dispatch) ===================
__global__ __launch_bounds__(256) void k_mega(
    const float* x0, const float* x1, const float* x2,
    const float* Wk, const float* bk, const float* Wq, const float* bq,
    const float* Wv, const float* bv, const float* Wa, const float* ba,
    const float* rel_att, const float* rel_msg, const float* rel_pri,
    const float* wm0, const float* wm1, const float* wm2,
    const float* skip, const int* src, const int* dst,
    float* out, unsigned short* P, unsigned short* Wt_all, float* bias_all,
    int* bar, int* allocg, int* counts, int* cursor, int* row_start,
    int* src_sorted, unsigned short* hagg, int N, int E)
{
  __shared__ __attribute__((aligned(16))) unsigned short Wt[128 * 136];
  int tid = threadIdx.x, bid = blockIdx.x, NB = gridDim.x;
  int gid = bid * 256 + tid, gstride = NB * 256;
  int wave = tid >> 6, lane = tid & 63;

  // P0: zero counts (+alloc via memset) and fold weights
  for (int i = gid; i < N; i += gstride) counts[i] = 0;
  for (int i = gid; i < 6 * 16384; i += gstride)
    fold_item(i, Wk, bk, Wq, bq, Wv, bv, rel_att, rel_msg, rel_pri,
              wm0, wm1, wm2, Wt_all, bias_all);
  gbar(bar + 0 * 16, NB);

  // P1: histogram + projection GEMMs (independent)
  for (int e = gid; e < E; e += gstride) atomicAdd(&counts[dst[e]], 1);
  int ntiles = ((N + 63) / 64) * 3;
  for (int t = bid; t < ntiles; t += NB)
    proj_tile(t, x0, x1, x2, Wt_all, bias_all, P, N, Wt, tid);
  gbar(bar + 1 * 16, NB);

  // P2: unordered CSR segment assignment
  int nchunks = (N + 63) / 64;
  for (int a = bid * 4 + wave; a < nchunks; a += NB * 4)
    assign_chunk(a, counts, row_start, cursor, allocg, N, lane);
  gbar(bar + 2 * 16, NB);

  // P3: scatter src ids into CSR order
  for (int e = gid; e < E; e += gstride) {
    int d = dst[e];
    int pos = atomicAdd(&cursor[d], 1);
    src_sorted[pos] = src[e];
  }
  gbar(bar + 3 * 16, NB);

  // P4: fused node attention + aggregation
  int ngroups = (N + 3) / 4;
  for (int g = bid; g < ngroups; g += NB) {
    int n = g * 4 + wave;
    if (n < N) node_one(n, P, row_start, counts, src_sorted, hagg, N, lane);
  }
  gbar(bar + 4 * 16, NB);

  // P5: output GEMM — stage Wa once, then tiles
  __syncthreads();
#pragma unroll
  for (int it = 0; it < 16; it++) {
    int idx = it * 256 + tid;
    int k = idx >> 5, c4 = (idx & 31) << 2;
    float4 w = *(const float4*)(&Wa[k * 128 + c4]);
    Wt[(c4 + 0) * 136 + k] = f2bf(w.x);
    Wt[(c4 + 1) * 136 + k] = f2bf(w.y);
    Wt[(c4 + 2) * 136 + k] = f2bf(w.z);
    Wt[(c4 + 3) * 136 + k] = f2bf(w.w);
  }
  __syncthreads();
  float alpha = 1.f / (1.f + __expf(-skip[0]));
  for (int t = bid; t < ntiles; t += NB)
    out_tile(t, hagg, ba, x0, x1, x2, alpha, out, N, Wt, tid);
}

// =============== fallback multi-kernel path (round-8 equivalent) ============
__global__ __launch_bounds__(256) void fb_misc(
    const float* Wk, const float* bk, const float* Wq, const float* bq,
    const float* Wv, const float* bv,
    const float* rel_att, const float* rel_msg, const float* rel_pri,
    const float* wm0, const float* wm1, const float* wm2,
    unsigned short* Wt_all, float* bias_all,
    const int* dst, int* counts, int E)
{
  int b = blockIdx.x;
  if (b < 384) {
    int g = b * 256 + threadIdx.x;
    if (g < 6 * 16384)
      fold_item(g, Wk, bk, Wq, bq, Wv, bv, rel_att, rel_msg, rel_pri,
                wm0, wm1, wm2, Wt_all, bias_all);
  } else {
    int e = (b - 384) * 256 + threadIdx.x;
    if (e < E) atomicAdd(&counts[dst[e]], 1);
  }
}

__global__ __launch_bounds__(256) void fb_projassign(
    const float* x0, const float* x1, const float* x2,
    const unsigned short* Wt_all, const float* bias_all,
    unsigned short* P, const int* counts, int* row_start, int* cursor,
    int* allocg, int N)
{
  __shared__ __attribute__((aligned(16))) unsigned short Wt[128 * 136];
  int ntiles = ((N + 63) / 64) * 3;
  int b = blockIdx.x;
  if (b < ntiles) {
    proj_tile(b, x0, x1, x2, Wt_all, bias_all, P, N, Wt, threadIdx.x);
  } else {
    int a = (b - ntiles) * 4 + (threadIdx.x >> 6);
    if (a < (N + 63) / 64)
      assign_chunk(a, counts, row_start, cursor, allocg, N, threadIdx.x & 63);
  }
}

__global__ void fb_scatter(const int* dst, const int* src, int* cursor,
                           int* src_sorted, int E) {
  int e = blockIdx.x * 256 + threadIdx.x;
  if (e < E) {
    int d = dst[e];
    int pos = atomicAdd(&cursor[d], 1);
    src_sorted[pos] = src[e];
  }
}

__global__ __launch_bounds__(256) void fb_node(
    const unsigned short* P, const int* row_start, const int* counts,
    const int* srcs, unsigned short* hagg, int N)
{
  int n = blockIdx.x * 4 + (threadIdx.x >> 6);
  if (n < N) node_one(n, P, row_start, counts, srcs, hagg, N, threadIdx.x & 63);
}

__global__ __launch_bounds__(256) void fb_out(
    const unsigned short* Hagg, const float* Wa, const float* ba,
    const float* x0, const float* x1, const float* x2, const float* skip,
    float* out, int N)
{
  __shared__ __attribute__((aligned(16))) unsigned short Wt[128 * 136];
  int tid = threadIdx.x;
#pragma unroll
  for (int it = 0; it < 16; it++) {
    int idx = it * 256 + tid;
    int k = idx >> 5, c4 = (idx & 31) << 2;
    float4 w = *(const float4*)(&Wa[k * 128 + c4]);
    Wt[(c4 + 0) * 136 + k] = f2bf(w.x);
    Wt[(c4 + 1) * 136 + k] = f2bf(w.y);
    Wt[(c4 + 2) * 136 + k] = f2bf(w.z);
    Wt[(c4 + 3) * 136 + k] = f2bf(w.w);
  }
  __syncthreads();
  float alpha = 1.f / (1.f + __expf(-skip[0]));
  out_tile(blockIdx.x, Hagg, ba, x0, x1, x2, alpha, out, N, Wt, tid);
}

// ---------------------------------------------------------------- launch
extern "C" void kernel_launch(void* const* d_in, const int* in_sizes, int n_in,
                              void* d_out, int out_size, void* d_ws, size_t ws_size,
                              hipStream_t stream) {
  const float* x0 = (const float*)d_in[0];
  const float* x1 = (const float*)d_in[1];
  const float* x2 = (const float*)d_in[2];
  const float* Wk = (const float*)d_in[3];
  const float* bk = (const float*)d_in[4];
  const float* Wq = (const float*)d_in[5];
  const float* bq = (const float*)d_in[6];
  const float* Wv = (const float*)d_in[7];
  const float* bv = (const float*)d_in[8];
  const float* Wa = (const float*)d_in[9];
  const float* ba = (const float*)d_in[10];
  const float* rel_att = (const float*)d_in[11];
  const float* rel_msg = (const float*)d_in[12];
  const float* rel_pri = (const float*)d_in[13];
  const float* wm0 = (const float*)d_in[14];
  const float* wm1 = (const float*)d_in[15];
  const float* wm2 = (const float*)d_in[16];
  const float* skip = (const float*)d_in[17];
  const int* src = (const int*)d_in[18];
  const int* dstv = (const int*)d_in[19];
  int N = in_sizes[0] / D;      // 20000
  int E = in_sizes[18];         // 160000

  char* wsb = (char*)d_ws;
  size_t off = 0;
  auto alloc_b = [&](size_t bytes) { size_t o = off; off += (bytes + 63) & ~(size_t)63; return o; };
  unsigned short* P         = (unsigned short*)(wsb + alloc_b((size_t)12 * N * D * 2));
  unsigned short* Wt_all    = (unsigned short*)(wsb + alloc_b((size_t)6 * 16384 * 2));
  float*          bias_all  = (float*)(wsb + alloc_b((size_t)6 * 128 * 4));
  // ctrl: bar[8*16] | alloc[16] | counts[N] | cursor[N]
  int*            ctrl      = (int*)(wsb + alloc_b(((size_t)144 + 2 * N) * 4));
  int*            row_start = (int*)(wsb + alloc_b((size_t)(N + 1) * 4));
  int*            src_sorted= (int*)(wsb + alloc_b((size_t)E * 4));
  unsigned short* hagg      = (unsigned short*)(wsb + alloc_b((size_t)3 * N * D * 2));
  int* bar    = ctrl;
  int* allocg = ctrl + 128;
  int* counts = ctrl + 144;
  int* cursor = ctrl + 144 + N;

  // zero barriers + alloc + counts (cursor written by assign phase)
  hipMemsetAsync(ctrl, 0, ((size_t)144 + N) * sizeof(int), stream);

  int nbPerCu = 0;
  hipError_t oe = hipOccupancyMaxActiveBlocksPerMultiprocessor(&nbPerCu, k_mega, 256, 0);
  if (oe == hipSuccess && nbPerCu >= 1) {
    int grid = nbPerCu * 256;          // MI355X: 256 CUs; grid == exact co-residency
    if (grid > 2048) grid = 2048;
    k_mega<<<dim3(grid), 256, 0, stream>>>(
        x0, x1, x2, Wk, bk, Wq, bq, Wv, bv, Wa, ba,
        rel_att, rel_msg, rel_pri, wm0, wm1, wm2, skip, src, dstv,
        (float*)d_out, P, Wt_all, bias_all,
        bar, allocg, counts, cursor, row_start, src_sorted, hagg, N, E);
  } else {
    int ntiles = ((N + 63) / 64) * 3;
    int nchunks = (N + 63) / 64;
    fb_misc<<<dim3(384 + (E + 255) / 256), 256, 0, stream>>>(
        Wk, bk, Wq, bq, Wv, bv, rel_att, rel_msg, rel_pri, wm0, wm1, wm2,
        Wt_all, bias_all, dstv, counts, E);
    fb_projassign<<<dim3(ntiles + (nchunks + 3) / 4), 256, 0, stream>>>(
        x0, x1, x2, Wt_all, bias_all, P, counts, row_start, cursor, allocg, N);
    fb_scatter<<<dim3((E + 255) / 256), 256, 0, stream>>>(
        dstv, src, cursor, src_sorted, E);
    fb_node<<<dim3((N + 3) / 4), 256, 0, stream>>>(
        P, row_start, counts, src_sorted, hagg, N);
    fb_out<<<dim3(ntiles), 256, 0, stream>>>(
        hagg, Wa, ba, x0, x1, x2, skip, (float*)d_out, N);
  }
}